// Round 6
// baseline (282.542 us; speedup 1.0000x reference)
//
#include <hip/hip_runtime.h>

constexpr int Tq = 2048;
constexpr int Dq = 1024;

typedef __bf16 bf16x8 __attribute__((ext_vector_type(8)));
typedef float f32x4 __attribute__((ext_vector_type(4)));
typedef _Float16 f16;
typedef f16 f16x4 __attribute__((ext_vector_type(4)));
typedef unsigned short u16;
typedef u16 u16x4 __attribute__((ext_vector_type(4)));
typedef u16 u16x8 __attribute__((ext_vector_type(8)));

__device__ __forceinline__ u16 f2bf(float f) {
    unsigned int u = __float_as_uint(f);
    u += 0x7fffu + ((u >> 16) & 1u);   // RNE
    return (u16)(u >> 16);
}

// async global->LDS, 16B per lane. LDS dest must be wave-uniform base + lane*16.
__device__ __forceinline__ void gld_lds16(const void* g, void* l) {
    __builtin_amdgcn_global_load_lds(
        (const __attribute__((address_space(1))) unsigned int*)g,
        (__attribute__((address_space(3))) unsigned int*)l, 16, 0, 0);
}

// ---------------- fp32 -> bf16 conversion (3 arrays, one launch) ------------
__global__ void cvt3_f32_bf16(const float* __restrict__ a, u16* __restrict__ oa, int na,
                              const float* __restrict__ b, u16* __restrict__ ob, int nb,
                              const float* __restrict__ c, u16* __restrict__ oc, int nc) {
    int i = blockIdx.x * 256 + threadIdx.x;
    const float* in; u16* out;
    if (i < na) { in = a; out = oa; }
    else if (i < na + nb) { in = b; out = ob; i -= na; }
    else if (i < na + nb + nc) { in = c; out = oc; i -= na + nb; }
    else return;
    float4 v = ((const float4*)in)[i];
    u16x4 o;
    o.x = f2bf(v.x); o.y = f2bf(v.y); o.z = f2bf(v.z); o.w = f2bf(v.w);
    ((u16x4*)out)[i] = o;
}

// ---------------- QKV GEMM: 256x256 tile, BK=64, counted-vmcnt schedule -----
// C[8192,3072] = xb * Wqkv^T.  512 thr = 8 waves (2 row x 4 col), per-wave
// 128x64 output (8 M-frags x 4 N-frags).  LDS: 2 x (A 256x64 + B 256x64) bf16
// = 128 KB, chunk-swizzled slot = gc ^ (row&7) (T2; linear gld_lds dest +
// pre-swizzled global source).  Per K-tile: 4 phases, 2 gld_lds each; gates
// are vmcnt(2)+s_barrier at tile entry (retires Bq0-3,Aq0,Aq2 of this tile)
// and vmcnt(2)+s_barrier mid-tile (retires Aq1,Aq3) -- loads stay in flight
// across barriers (T3+T4), setprio around MFMA clusters (T5).
// blockIdx.y 0-3 -> Q (rope+scale), 4-7 -> K (rope), 8-11 -> V (transposed f16).
// Each wave's 64 cols = exactly one head; (d, d+32) sit in frags n and n+2.
__global__ __launch_bounds__(512, 2) void gemm_qkv(const u16* __restrict__ A,
                                                   const u16* __restrict__ B,
                                                   const float* __restrict__ cosT,
                                                   const float* __restrict__ sinT,
                                                   u16* __restrict__ Qb,
                                                   u16* __restrict__ Kb,
                                                   f16* __restrict__ Vtg) {
    constexpr int K = 1024, nk = K / 64;
    __shared__ __align__(16) u16 smem[65536];          // 128 KB: 2 x (As 32K + Bs 32K)
    const int t = threadIdx.x;
    const int lane = t & 63;
    const int wave = t >> 6;
    const int l16 = lane & 15;
    const int quad = lane >> 4;
    const int wr = wave >> 2;                          // 0..1  (row wave)
    const int wc = wave & 3;                           // 0..3  (col wave)
    const int bm = blockIdx.x * 256;
    const int by = blockIdx.y;
    const int bn = by * 256;

    // staging: unit = 64 rows x 64 cols = 8 KB = one gld_lds issue (512 lanes x 16B)
    const int srow = t >> 3;                           // row within unit
    const int sgc = (t & 7) ^ (srow & 7);              // pre-swizzled global chunk
    const u16* Ab = A + (size_t)(bm + srow) * K + sgc * 8;
    const u16* Bb = B + (size_t)(bn + srow) * K + sgc * 8;

    f32x4 acc[8][4] = {};

    auto stageA = [&](int kt, int q) {
        gld_lds16(Ab + (size_t)q * 64 * K + kt * 64,
                  (char*)smem + (kt & 1) * 65536 + q * 8192 + t * 16);
    };
    auto stageB = [&](int kt, int q) {
        gld_lds16(Bb + (size_t)q * 64 * K + kt * 64,
                  (char*)smem + (kt & 1) * 65536 + 32768 + q * 8192 + t * 16);
    };

    // prologue: tile 0, order matters (oldest 6 = what G1 gates)
    stageB(0, 0); stageB(0, 1); stageB(0, 2); stageB(0, 3);
    stageA(0, 0); stageA(0, 2); stageA(0, 1); stageA(0, 3);

    const int cc0 = quad ^ (l16 & 7);                  // ks=0 swizzled slot
    const int cc1 = (4 + quad) ^ (l16 & 7);            // ks=1 swizzled slot

    for (int kt = 0; kt < nk; kt++) {
        const u16* As = smem + (kt & 1) * 32768;
        const u16* Bs = As + 16384;
        const bool pre = (kt + 1 < nk);

        // G1: gates Bq0-3, Aq0, Aq2 of this tile (leaves newest 2 in flight)
        asm volatile("s_waitcnt vmcnt(2)\n\ts_barrier" ::: "memory");

        bf16x8 af[4], bf[4];
        // ---- phase 0: m0-3 x ks0 ----
        if (pre) { stageB(kt + 1, 0); stageB(kt + 1, 1); }
#pragma unroll
        for (int m = 0; m < 4; m++)
            af[m] = *(const bf16x8*)&As[(wr * 128 + m * 16 + l16) * 64 + cc0 * 8];
#pragma unroll
        for (int n = 0; n < 4; n++)
            bf[n] = *(const bf16x8*)&Bs[(wc * 64 + n * 16 + l16) * 64 + cc0 * 8];
        __builtin_amdgcn_s_setprio(1);
#pragma unroll
        for (int m = 0; m < 4; m++)
#pragma unroll
            for (int n = 0; n < 4; n++)
                acc[m][n] = __builtin_amdgcn_mfma_f32_16x16x32_bf16(af[m], bf[n], acc[m][n], 0, 0, 0);
        __builtin_amdgcn_s_setprio(0);

        // G_mid: gates Aq1, Aq3 of this tile
        if (pre) asm volatile("s_waitcnt vmcnt(2)\n\ts_barrier" ::: "memory");
        else     asm volatile("s_waitcnt vmcnt(0)\n\ts_barrier" ::: "memory");

        // ---- phase 1: m4-7 x ks0 ----
        if (pre) { stageB(kt + 1, 2); stageB(kt + 1, 3); }
#pragma unroll
        for (int m = 0; m < 4; m++)
            af[m] = *(const bf16x8*)&As[(wr * 128 + (m + 4) * 16 + l16) * 64 + cc0 * 8];
        __builtin_amdgcn_s_setprio(1);
#pragma unroll
        for (int m = 0; m < 4; m++)
#pragma unroll
            for (int n = 0; n < 4; n++)
                acc[m + 4][n] = __builtin_amdgcn_mfma_f32_16x16x32_bf16(af[m], bf[n], acc[m + 4][n], 0, 0, 0);
        __builtin_amdgcn_s_setprio(0);

        // ---- phase 2: m0-3 x ks1 ----
        if (pre) { stageA(kt + 1, 0); stageA(kt + 1, 2); }
#pragma unroll
        for (int m = 0; m < 4; m++)
            af[m] = *(const bf16x8*)&As[(wr * 128 + m * 16 + l16) * 64 + cc1 * 8];
#pragma unroll
        for (int n = 0; n < 4; n++)
            bf[n] = *(const bf16x8*)&Bs[(wc * 64 + n * 16 + l16) * 64 + cc1 * 8];
        __builtin_amdgcn_s_setprio(1);
#pragma unroll
        for (int m = 0; m < 4; m++)
#pragma unroll
            for (int n = 0; n < 4; n++)
                acc[m][n] = __builtin_amdgcn_mfma_f32_16x16x32_bf16(af[m], bf[n], acc[m][n], 0, 0, 0);
        __builtin_amdgcn_s_setprio(0);

        // ---- phase 3: m4-7 x ks1 ----
        if (pre) { stageA(kt + 1, 1); stageA(kt + 1, 3); }
#pragma unroll
        for (int m = 0; m < 4; m++)
            af[m] = *(const bf16x8*)&As[(wr * 128 + (m + 4) * 16 + l16) * 64 + cc1 * 8];
        __builtin_amdgcn_s_setprio(1);
#pragma unroll
        for (int m = 0; m < 4; m++)
#pragma unroll
            for (int n = 0; n < 4; n++)
                acc[m + 4][n] = __builtin_amdgcn_mfma_f32_16x16x32_bf16(af[m], bf[n], acc[m + 4][n], 0, 0, 0);
        __builtin_amdgcn_s_setprio(0);
    }

    // ---------------- fused epilogue ----------------
    const int kind = by >> 2;                   // 0=Q 1=K 2=V
    if (kind < 2) {
        u16* Out = kind ? Kb : Qb;
        const float qscale = kind ? 1.f : 0.18033688011112042f;  // 0.125*log2(e)
        const int h = ((by & 3) << 2) + wc;
#pragma unroll
        for (int m = 0; m < 8; m++)
#pragma unroll
            for (int r = 0; r < 4; r++) {
                const int gm = bm + wr * 128 + m * 16 + quad * 4 + r;
                const int b = gm >> 11, tt = gm & 2047;
                const size_t row = ((size_t)(b * 16 + h) * Tq + tt) * 64;
#pragma unroll
                for (int jj = 0; jj < 2; jj++) {
                    const int dd = jj * 16 + l16;            // 0..31
                    const float c = cosT[tt * 32 + dd];
                    const float s = sinT[tt * 32 + dd];
                    const float v1 = acc[m][jj][r];
                    const float v2 = acc[m][jj + 2][r];
                    Out[row + dd]      = f2bf((v1 * c - v2 * s) * qscale);
                    Out[row + dd + 32] = f2bf((v1 * s + v2 * c) * qscale);
                }
            }
    } else {
        // V: write transposed (bh, d, t) in f16; f16x4 contiguous along t
        const int h = ((by & 3) << 2) + wc;
#pragma unroll
        for (int m = 0; m < 8; m++) {
            const int gm0 = bm + wr * 128 + m * 16 + quad * 4;
            const int b = gm0 >> 11, tt = gm0 & 2047;
#pragma unroll
            for (int n = 0; n < 4; n++) {
                const int d = n * 16 + l16;                  // 0..63
                f16x4 o = {(f16)acc[m][n][0], (f16)acc[m][n][1],
                           (f16)acc[m][n][2], (f16)acc[m][n][3]};
                *(f16x4*)&Vtg[((size_t)(b * 16 + h) * 64 + d) * Tq + tt] = o;
            }
        }
    }
}

// ---------------- GEMM: C[M,N] = A[M,K] * B[N,K]^T (m97 structure) ----------
__global__ __launch_bounds__(256) void gemm_bt(const u16* __restrict__ A,
                                               const u16* __restrict__ B,
                                               float* __restrict__ Cv,
                                               int M, int N, int K) {
    __shared__ u16 As[128 * 32];
    __shared__ u16 Bs[128 * 32];
    const int t = threadIdx.x;
    const int lane = t & 63;
    const int wave = t >> 6;
    const int l16 = lane & 15;
    const int quad = lane >> 4;
    const int bm = blockIdx.x * 128;
    const int bn = blockIdx.y * 128;
    const int wm = (wave & 1) * 64;
    const int wn = (wave >> 1) * 64;
    const int srow = t >> 2;
    const int scol = (t & 3) * 8;

    f32x4 acc[4][4] = {};

    const u16* Ab = A + (size_t)(bm + srow) * K + scol;
    const u16* Bb = B + (size_t)(bn + srow) * K + scol;

    for (int k0 = 0; k0 < K; k0 += 32) {
        gld_lds16(Ab + k0,                    (char*)As + t * 16);
        gld_lds16(Ab + (size_t)64 * K + k0,   (char*)As + 4096 + t * 16);
        gld_lds16(Bb + k0,                    (char*)Bs + t * 16);
        gld_lds16(Bb + (size_t)64 * K + k0,   (char*)Bs + 4096 + t * 16);
        __syncthreads();

        bf16x8 af[4], bf[4];
#pragma unroll
        for (int i = 0; i < 4; i++) {
            af[i] = *(const bf16x8*)&As[(wm + i * 16 + l16) * 32 + quad * 8];
            bf[i] = *(const bf16x8*)&Bs[(wn + i * 16 + l16) * 32 + quad * 8];
        }
#pragma unroll
        for (int i = 0; i < 4; i++)
#pragma unroll
            for (int j = 0; j < 4; j++)
                acc[i][j] = __builtin_amdgcn_mfma_f32_16x16x32_bf16(af[i], bf[j], acc[i][j], 0, 0, 0);
        __syncthreads();
    }

#pragma unroll
    for (int i = 0; i < 4; i++)
#pragma unroll
        for (int j = 0; j < 4; j++)
#pragma unroll
            for (int r = 0; r < 4; r++) {
                const int gm = bm + wm + i * 16 + quad * 4 + r;
                const int gn = bn + wn + j * 16 + l16;
                Cv[(size_t)gm * N + gn] = acc[i][j][r];
            }
}

// ---------------- flash attention: S^T form, constant-max softmax -----------
template <bool MASK>
__device__ __forceinline__ void flash_tile(const u16* __restrict__ Ks,
                                           const f16* __restrict__ Vs,
                                           const bf16x8& qf0, const bf16x8& qf1,
                                           int l16, int quad, int i_loc,
                                           float& l_run, f32x4* o_acc) {
    f32x4 s[4];
    const int cp0 = quad ^ (l16 & 7);
    const int cp1 = (4 + quad) ^ (l16 & 7);
    __builtin_amdgcn_s_setprio(1);
#pragma unroll
    for (int tn = 0; tn < 4; tn++) {
        const int jrow = tn * 16 + l16;
        bf16x8 kf0 = *(const bf16x8*)&Ks[jrow * 64 + cp0 * 8];
        bf16x8 kf1 = *(const bf16x8*)&Ks[jrow * 64 + cp1 * 8];
        f32x4 z = {0.f, 0.f, 0.f, 0.f};
        z = __builtin_amdgcn_mfma_f32_16x16x32_bf16(kf0, qf0, z, 0, 0, 0);
        z = __builtin_amdgcn_mfma_f32_16x16x32_bf16(kf1, qf1, z, 0, 0, 0);
        s[tn] = z;
    }
    __builtin_amdgcn_s_setprio(0);
    float rsa[4];
#pragma unroll
    for (int tn = 0; tn < 4; tn++) {
        float rs = 0.f;
#pragma unroll
        for (int r = 0; r < 4; r++) {
            float v = s[tn][r];
            if (MASK) {
                const int j_loc = tn * 16 + quad * 4 + r;
                if (j_loc > i_loc) v = -1e30f;     // causal mask
            }
            float p = exp2f(v);
            rs += p;                               // l includes the diagonal...
            if (MASK) {
                const int j_loc = tn * 16 + quad * 4 + r;
                if (j_loc == i_loc) p = 0.f;       // ...PV excludes it (== out - self_w*v)
            }
            s[tn][r] = p;
        }
        rsa[tn] = rs;
    }
    l_run += (rsa[0] + rsa[1]) + (rsa[2] + rsa[3]);

    f16x4 pf[4];
#pragma unroll
    for (int tk = 0; tk < 4; tk++)
        pf[tk] = f16x4{(f16)s[tk][0], (f16)s[tk][1], (f16)s[tk][2], (f16)s[tk][3]};
    __builtin_amdgcn_s_setprio(1);
#pragma unroll
    for (int td = 0; td < 4; td++) {
        const int drow = td * 16 + l16;
#pragma unroll
        for (int tk = 0; tk < 4; tk++) {
            const int cp = (2 * tk + (quad >> 1)) ^ (l16 & 7);
            f16x4 vf = *(const f16x4*)&Vs[drow * 64 + cp * 8 + (quad & 1) * 4];
            o_acc[td] = __builtin_amdgcn_mfma_f32_16x16x16f16(vf, pf[tk], o_acc[td], 0, 0, 0);
        }
    }
    __builtin_amdgcn_s_setprio(0);
}

// 512 threads = 8 waves. In-block complementary q-tiles: waves 0-3 own tile x,
// waves 4-7 own tile 31-x => per-block work = 33 wave-tiles = constant; each
// SIMD hosts one short + one long wave. 3-deep LDS ring (48KB) -> 3 blocks/CU
// (24 waves, 75% occ cap) so co-resident blocks fill barrier-idle slots.
// stage(n+2) is issued AFTER the gate barrier: its buffer (n+2)%3 was last
// read by compute(n-1), which every wave finished before barrier(n) => safe.
// vmcnt ledger: at gate(n) only stage(n+1)'s 2 loads may remain in flight.
// XCD-swizzled: head bh entirely on XCD bh>>3 (KV working set = 4MB = L2).
__global__ __launch_bounds__(512, 6) void flash(const u16* __restrict__ Qb,
                                                const u16* __restrict__ Kb,
                                                const f16* __restrict__ Vtg,
                                                u16* __restrict__ Ob) {
    __shared__ __align__(16) char smem[49152];   // 3 x (K 8KB + V 8KB)

    const int t = threadIdx.x, lane = t & 63, wave = t >> 6;
    const int l16 = lane & 15, quad = lane >> 4;
    const int i = blockIdx.x;                    // 0..1023
    const int xcd = i & 7, w = i >> 3;           // w: 0..127
    const int bh = xcd * 8 + (w >> 4);           // 8 heads per XCD
    const int b = bh >> 4, h = bh & 15;
    const int x = w & 15;
    const int qt = (wave < 4) ? x : (31 - x);    // this wave's 64-query tile
    const int q0w = qt * 64;
    const u16* Qp = Qb + (size_t)bh * Tq * 64;
    const u16* Kp = Kb + (size_t)bh * Tq * 64;
    const f16* Vp = Vtg + (size_t)bh * 64 * Tq;

    const int i_abs = q0w + (wave & 3) * 16 + l16;
    bf16x8 qf0 = *(const bf16x8*)(Qp + (size_t)i_abs * 64 + quad * 8);
    bf16x8 qf1 = *(const bf16x8*)(Qp + (size_t)i_abs * 64 + 32 + quad * 8);
    // pin Q-frag loads complete so manual vmcnt bookkeeping below is exact
    asm volatile("s_waitcnt vmcnt(0)" : "+v"(qf0), "+v"(qf1) :: "memory");

    float l_run = 0.f;
    f32x4 o_acc[4] = {};

    const int srow = t >> 3;                     // 0..63 (512 threads)
    const int sc = (t & 7) ^ (srow & 7);         // swizzled chunk slot
    const int diag_n = qt;                       // this wave's diagonal tile
    const int i_tloc = (wave & 3) * 16 + l16;    // query pos within the tile
    const int nt = 32 - x;                       // tiles 0 .. 31-x  (nt >= 17)

    auto stage = [&](int n, int bi) {            // 2 loads -> vmcnt +2
        const int j0 = n * 64;
        char* buf = smem + bi * 16384;
        gld_lds16(Kp + (size_t)(j0 + srow) * 64 + sc * 8, buf + t * 16);
        gld_lds16(Vp + (size_t)srow * Tq + j0 + sc * 8,   buf + 8192 + t * 16);
    };

    stage(0, 0);
    stage(1, 1);
    int cur = 0;                                 // n % 3
    for (int n = 0; n < nt; n++) {
        // gate(n): stage(n) must be retired; stage(n+1) stays in flight.
        if (n + 1 < nt)
            asm volatile("s_waitcnt vmcnt(2)\n\ts_barrier" ::: "memory");
        else
            asm volatile("s_waitcnt vmcnt(0)\n\ts_barrier" ::: "memory");
        if (n + 2 < nt)
            stage(n + 2, cur == 0 ? 2 : cur - 1);   // (n+2)%3 == (cur+2)%3
        char* cb = smem + cur * 16384;
        const u16* Ks = (const u16*)cb;
        const f16* Vs = (const f16*)(cb + 8192);
        if (n < diag_n)
            flash_tile<false>(Ks, Vs, qf0, qf1, l16, quad, i_tloc, l_run, o_acc);
        else if (n == diag_n)
            flash_tile<true>(Ks, Vs, qf0, qf1, l16, quad, i_tloc, l_run, o_acc);
        // waves with n > diag_n skip compute but still hit the barrier
        cur = (cur == 2) ? 0 : cur + 1;
    }

    // reduce l across the 4 quads sharing each query (once, not per tile)
    l_run += __shfl_xor(l_run, 16, 64);
    l_run += __shfl_xor(l_run, 32, 64);
    const float inv_l = 1.f / l_run;

    // epilogue: O^T -> O via padded LDS (stride 72), coalesced bf16 stores
    __syncthreads();                             // all waves done reading ring
    u16* Os = (u16*)smem;                        // 8 waves * 16 * 72 u16 = 18KB
#pragma unroll
    for (int td = 0; td < 4; td++) {
        u16x4 o;
#pragma unroll
        for (int r = 0; r < 4; r++) o[r] = f2bf(o_acc[td][r] * inv_l);
        *(u16x4*)&Os[wave * 1152 + l16 * 72 + td * 16 + quad * 4] = o;
    }
    __syncthreads();
    const int oi = lane >> 2, od = (lane & 3) * 16;
    u16x8 r0 = *(const u16x8*)&Os[wave * 1152 + oi * 72 + od];
    u16x8 r1 = *(const u16x8*)&Os[wave * 1152 + oi * 72 + od + 8];
    const size_t orow = ((size_t)b * Tq + q0w + (wave & 3) * 16 + oi) * Dq + h * 64 + od;
    *(u16x8*)&Ob[orow] = r0;
    *(u16x8*)&Ob[orow + 8] = r1;
}

// ---------------- launch ----------------
extern "C" void kernel_launch(void* const* d_in, const int* in_sizes, int n_in,
                              void* d_out, int out_size, void* d_ws, size_t ws_size,
                              hipStream_t stream) {
    const float* x     = (const float*)d_in[0];
    const float* cosT  = (const float*)d_in[1];
    const float* sinT  = (const float*)d_in[2];
    const float* Wqkv  = (const float*)d_in[3];
    const float* Wproj = (const float*)d_in[4];

    u16* xb     = (u16*)d_ws;                          // 8192*1024
    u16* wqkvb  = xb + (size_t)8192 * 1024;            // 3072*1024
    u16* wprojb = wqkvb + (size_t)3072 * 1024;         // 1024*1024
    u16* Qb     = wprojb + (size_t)1024 * 1024;        // 64*2048*64
    u16* Kb     = Qb + (size_t)64 * 2048 * 64;         // 64*2048*64
    f16* Vtg    = (f16*)(Kb + (size_t)64 * 2048 * 64); // 64*64*2048 (transposed)
    u16* attn   = (u16*)(Vtg + (size_t)64 * 64 * 2048);// 8192*1024

    cvt3_f32_bf16<<<12288, 256, 0, stream>>>(x, xb, 2097152,
                                             Wqkv, wqkvb, 786432,
                                             Wproj, wprojb, 262144);

    gemm_qkv<<<dim3(32, 12), 512, 0, stream>>>(xb, wqkvb, cosT, sinT, Qb, Kb, Vtg);
    flash<<<1024, 512, 0, stream>>>(Qb, Kb, Vtg, attn);
    gemm_bt<<<dim3(64, 8), 256, 0, stream>>>(attn, wprojb, (float*)d_out, 8192, 1024, 1024);
}

// Round 9
// 263.023 us; speedup vs baseline: 1.0742x; 1.0742x over previous
//
#include <hip/hip_runtime.h>

constexpr int Tq = 2048;
constexpr int Dq = 1024;

typedef __bf16 bf16x8 __attribute__((ext_vector_type(8)));
typedef float f32x4 __attribute__((ext_vector_type(4)));
typedef _Float16 f16;
typedef f16 f16x4 __attribute__((ext_vector_type(4)));
typedef unsigned short u16;
typedef u16 u16x4 __attribute__((ext_vector_type(4)));
typedef u16 u16x8 __attribute__((ext_vector_type(8)));

__device__ __forceinline__ u16 f2bf(float f) {
    unsigned int u = __float_as_uint(f);
    u += 0x7fffu + ((u >> 16) & 1u);   // RNE
    return (u16)(u >> 16);
}

// async global->LDS, 16B per lane. LDS dest must be wave-uniform base + lane*16.
__device__ __forceinline__ void gld_lds16(const void* g, void* l) {
    __builtin_amdgcn_global_load_lds(
        (const __attribute__((address_space(1))) unsigned int*)g,
        (__attribute__((address_space(3))) unsigned int*)l, 16, 0, 0);
}

// ---------------- fp32 -> bf16 conversion (3 arrays, one launch) ------------
__global__ void cvt3_f32_bf16(const float* __restrict__ a, u16* __restrict__ oa, int na,
                              const float* __restrict__ b, u16* __restrict__ ob, int nb,
                              const float* __restrict__ c, u16* __restrict__ oc, int nc) {
    int i = blockIdx.x * 256 + threadIdx.x;
    const float* in; u16* out;
    if (i < na) { in = a; out = oa; }
    else if (i < na + nb) { in = b; out = ob; i -= na; }
    else if (i < na + nb + nc) { in = c; out = oc; i -= na + nb; }
    else return;
    float4 v = ((const float4*)in)[i];
    u16x4 o;
    o.x = f2bf(v.x); o.y = f2bf(v.y); o.z = f2bf(v.z); o.w = f2bf(v.w);
    ((u16x4*)out)[i] = o;
}

// ---------------- QKV GEMM with fused RoPE + scatter epilogue ----------------
// C[8192,3072] = xb * Wqkv^T. blockIdx.y: 0..7 -> Q (rope+scale), 8..15 -> K
// (rope), 16..23 -> V (transposed f16). A 128-col tile never straddles Q/K/V,
// and d & d+32 of one head land in the SAME lane (sub-tiles j and j+2).
// (128^2 m97 structure, 1536 blocks = 2 full occupancy rounds @3/CU --
// measured better than the 256^2 384-block version: 255.6 vs 267.4 total.)
__global__ __launch_bounds__(256) void gemm_qkv(const u16* __restrict__ A,
                                                const u16* __restrict__ B,
                                                const float* __restrict__ cosT,
                                                const float* __restrict__ sinT,
                                                u16* __restrict__ Qb,
                                                u16* __restrict__ Kb,
                                                f16* __restrict__ Vtg) {
    constexpr int K = 1024, N = 3072;
    __shared__ u16 As[128 * 32];
    __shared__ u16 Bs[128 * 32];
    const int t = threadIdx.x;
    const int lane = t & 63;
    const int wave = t >> 6;
    const int l16 = lane & 15;
    const int quad = lane >> 4;
    const int bm = blockIdx.x * 128;
    const int by = blockIdx.y;
    const int bn = by * 128;
    const int wm = (wave & 1) * 64;
    const int wn = (wave >> 1) * 64;
    const int srow = t >> 2;
    const int scol = (t & 3) * 8;

    f32x4 acc[4][4] = {};

    const u16* Ab = A + (size_t)(bm + srow) * K + scol;
    const u16* Bb = B + (size_t)(bn + srow) * K + scol;

    for (int k0 = 0; k0 < K; k0 += 32) {
        gld_lds16(Ab + k0,                    (char*)As + t * 16);
        gld_lds16(Ab + (size_t)64 * K + k0,   (char*)As + 4096 + t * 16);
        gld_lds16(Bb + k0,                    (char*)Bs + t * 16);
        gld_lds16(Bb + (size_t)64 * K + k0,   (char*)Bs + 4096 + t * 16);
        __syncthreads();

        bf16x8 af[4], bf[4];
#pragma unroll
        for (int i = 0; i < 4; i++) {
            af[i] = *(const bf16x8*)&As[(wm + i * 16 + l16) * 32 + quad * 8];
            bf[i] = *(const bf16x8*)&Bs[(wn + i * 16 + l16) * 32 + quad * 8];
        }
#pragma unroll
        for (int i = 0; i < 4; i++)
#pragma unroll
            for (int j = 0; j < 4; j++)
                acc[i][j] = __builtin_amdgcn_mfma_f32_16x16x32_bf16(af[i], bf[j], acc[i][j], 0, 0, 0);
        __syncthreads();
    }

    const int kind = by >> 3;                   // 0=Q 1=K 2=V
    if (kind < 2) {
        // rope: pairs (j, j+2) give (d, d+32) of head h in the same lane
        u16* Out = kind ? Kb : Qb;
        const float qscale = kind ? 1.f : 0.18033688011112042f;  // 0.125*log2(e)
        const int h = ((by & 7) << 1) + (wn >> 6);
#pragma unroll
        for (int i = 0; i < 4; i++)
#pragma unroll
            for (int r = 0; r < 4; r++) {
                const int gm = bm + wm + i * 16 + quad * 4 + r;
                const int b = gm >> 11, tt = gm & 2047;
                const size_t row = ((size_t)(b * 16 + h) * Tq + tt) * 64;
#pragma unroll
                for (int jj = 0; jj < 2; jj++) {
                    const int dd = jj * 16 + l16;            // 0..31
                    const float c = cosT[tt * 32 + dd];
                    const float s = sinT[tt * 32 + dd];
                    const float v1 = acc[i][jj][r];
                    const float v2 = acc[i][jj + 2][r];
                    Out[row + dd]      = f2bf((v1 * c - v2 * s) * qscale);
                    Out[row + dd + 32] = f2bf((v1 * s + v2 * c) * qscale);
                }
            }
    } else {
        // V: write transposed (bh, d, t) in f16; f16x4 contiguous along t
#pragma unroll
        for (int i = 0; i < 4; i++) {
            const int gm0 = bm + wm + i * 16 + quad * 4;
            const int b = gm0 >> 11, tt = gm0 & 2047;
#pragma unroll
            for (int j = 0; j < 4; j++) {
                const int col = wn + j * 16 + l16;           // 0..127
                const int h = ((by & 7) << 1) + (col >> 6);
                const int d = col & 63;
                f16x4 o = {(f16)acc[i][j][0], (f16)acc[i][j][1],
                           (f16)acc[i][j][2], (f16)acc[i][j][3]};
                *(f16x4*)&Vtg[((size_t)(b * 16 + h) * 64 + d) * Tq + tt] = o;
            }
        }
    }
}

// ---------------- GEMM: C[M,N] = A[M,K] * B[N,K]^T (m97 structure) ----------
__global__ __launch_bounds__(256) void gemm_bt(const u16* __restrict__ A,
                                               const u16* __restrict__ B,
                                               float* __restrict__ Cv,
                                               int M, int N, int K) {
    __shared__ u16 As[128 * 32];
    __shared__ u16 Bs[128 * 32];
    const int t = threadIdx.x;
    const int lane = t & 63;
    const int wave = t >> 6;
    const int l16 = lane & 15;
    const int quad = lane >> 4;
    const int bm = blockIdx.x * 128;
    const int bn = blockIdx.y * 128;
    const int wm = (wave & 1) * 64;
    const int wn = (wave >> 1) * 64;
    const int srow = t >> 2;
    const int scol = (t & 3) * 8;

    f32x4 acc[4][4] = {};

    const u16* Ab = A + (size_t)(bm + srow) * K + scol;
    const u16* Bb = B + (size_t)(bn + srow) * K + scol;

    for (int k0 = 0; k0 < K; k0 += 32) {
        gld_lds16(Ab + k0,                    (char*)As + t * 16);
        gld_lds16(Ab + (size_t)64 * K + k0,   (char*)As + 4096 + t * 16);
        gld_lds16(Bb + k0,                    (char*)Bs + t * 16);
        gld_lds16(Bb + (size_t)64 * K + k0,   (char*)Bs + 4096 + t * 16);
        __syncthreads();

        bf16x8 af[4], bf[4];
#pragma unroll
        for (int i = 0; i < 4; i++) {
            af[i] = *(const bf16x8*)&As[(wm + i * 16 + l16) * 32 + quad * 8];
            bf[i] = *(const bf16x8*)&Bs[(wn + i * 16 + l16) * 32 + quad * 8];
        }
#pragma unroll
        for (int i = 0; i < 4; i++)
#pragma unroll
            for (int j = 0; j < 4; j++)
                acc[i][j] = __builtin_amdgcn_mfma_f32_16x16x32_bf16(af[i], bf[j], acc[i][j], 0, 0, 0);
        __syncthreads();
    }

#pragma unroll
    for (int i = 0; i < 4; i++)
#pragma unroll
        for (int j = 0; j < 4; j++)
#pragma unroll
            for (int r = 0; r < 4; r++) {
                const int gm = bm + wm + i * 16 + quad * 4 + r;
                const int gn = bn + wn + j * 16 + l16;
                Cv[(size_t)gm * N + gn] = acc[i][j][r];
            }
}

// ---------------- flash attention: S^T form, constant-max softmax -----------
template <bool MASK>
__device__ __forceinline__ void flash_tile(const u16* __restrict__ Ks,
                                           const f16* __restrict__ Vs,
                                           const bf16x8& qf0, const bf16x8& qf1,
                                           int l16, int quad, int i_loc,
                                           float& l_run, f32x4* o_acc) {
    f32x4 s[4];
    const int cp0 = quad ^ (l16 & 7);
    const int cp1 = (4 + quad) ^ (l16 & 7);
    __builtin_amdgcn_s_setprio(1);
#pragma unroll
    for (int tn = 0; tn < 4; tn++) {
        const int jrow = tn * 16 + l16;
        bf16x8 kf0 = *(const bf16x8*)&Ks[jrow * 64 + cp0 * 8];
        bf16x8 kf1 = *(const bf16x8*)&Ks[jrow * 64 + cp1 * 8];
        f32x4 z = {0.f, 0.f, 0.f, 0.f};
        z = __builtin_amdgcn_mfma_f32_16x16x32_bf16(kf0, qf0, z, 0, 0, 0);
        z = __builtin_amdgcn_mfma_f32_16x16x32_bf16(kf1, qf1, z, 0, 0, 0);
        s[tn] = z;
    }
    __builtin_amdgcn_s_setprio(0);
    float rsa[4];
#pragma unroll
    for (int tn = 0; tn < 4; tn++) {
        float rs = 0.f;
#pragma unroll
        for (int r = 0; r < 4; r++) {
            float v = s[tn][r];
            if (MASK) {
                const int j_loc = tn * 16 + quad * 4 + r;
                if (j_loc > i_loc) v = -1e30f;     // causal mask
            }
            float p = exp2f(v);
            rs += p;                               // l includes the diagonal...
            if (MASK) {
                const int j_loc = tn * 16 + quad * 4 + r;
                if (j_loc == i_loc) p = 0.f;       // ...PV excludes it (== out - self_w*v)
            }
            s[tn][r] = p;
        }
        rsa[tn] = rs;
    }
    l_run += (rsa[0] + rsa[1]) + (rsa[2] + rsa[3]);

    f16x4 pf[4];
#pragma unroll
    for (int tk = 0; tk < 4; tk++)
        pf[tk] = f16x4{(f16)s[tk][0], (f16)s[tk][1], (f16)s[tk][2], (f16)s[tk][3]};
    __builtin_amdgcn_s_setprio(1);
#pragma unroll
    for (int td = 0; td < 4; td++) {
        const int drow = td * 16 + l16;
#pragma unroll
        for (int tk = 0; tk < 4; tk++) {
            const int cp = (2 * tk + (quad >> 1)) ^ (l16 & 7);
            f16x4 vf = *(const f16x4*)&Vs[drow * 64 + cp * 8 + (quad & 1) * 4];
            o_acc[td] = __builtin_amdgcn_mfma_f32_16x16x16f16(vf, pf[tk], o_acc[td], 0, 0, 0);
        }
    }
    __builtin_amdgcn_s_setprio(0);
}

// 512 threads = 8 waves. Complementary q-tiles (waves 0-3: x, 4-7: 31-x).
// KVBLK=128 per iteration: ring-2 of 32KB buffers, each = [K0 8K][K1 8K]
// [V0 8K][V1 8K] (two 64x64 sub-tiles, flash_tile layout unchanged).
// Halved barrier count vs KVBLK=64 ring-4 (9-16 vs 17-32 gates/block) at the
// SAME 64KB LDS / 2 blocks/CU (ring-3's 3 blocks/CU thrashed L2: FETCH +34%,
// WRITE 2x -- keep memory pressure at the measured-best level).
// stage(n2+1) issued AFTER barrier(n2): its buffer's last reader was
// compute(n2-1), complete before barrier(n2). Gate = vmcnt(0)+barrier; the
// 4 in-flight loads get a full iteration (~2 tile-computes) to land.
// XCD-swizzled: head bh entirely on XCD bh>>3 (KV working set = 4MB = L2).
__global__ __launch_bounds__(512, 4) void flash(const u16* __restrict__ Qb,
                                                const u16* __restrict__ Kb,
                                                const f16* __restrict__ Vtg,
                                                u16* __restrict__ Ob) {
    __shared__ __align__(16) char smem[65536];   // 2 x 32KB

    const int t = threadIdx.x, lane = t & 63, wave = t >> 6;
    const int l16 = lane & 15, quad = lane >> 4;
    const int i = blockIdx.x;                    // 0..1023
    const int xcd = i & 7, w = i >> 3;           // w: 0..127
    const int bh = xcd * 8 + (w >> 4);           // 8 heads per XCD
    const int b = bh >> 4, h = bh & 15;
    const int x = w & 15;
    const int qt = (wave < 4) ? x : (31 - x);    // this wave's 64-query tile
    const int q0w = qt * 64;
    const u16* Qp = Qb + (size_t)bh * Tq * 64;
    const u16* Kp = Kb + (size_t)bh * Tq * 64;
    const f16* Vp = Vtg + (size_t)bh * 64 * Tq;

    const int i_abs = q0w + (wave & 3) * 16 + l16;
    bf16x8 qf0 = *(const bf16x8*)(Qp + (size_t)i_abs * 64 + quad * 8);
    bf16x8 qf1 = *(const bf16x8*)(Qp + (size_t)i_abs * 64 + 32 + quad * 8);
    // pin Q-frag loads complete so manual vmcnt bookkeeping below is exact
    asm volatile("s_waitcnt vmcnt(0)" : "+v"(qf0), "+v"(qf1) :: "memory");

    float l_run = 0.f;
    f32x4 o_acc[4] = {};

    const int srow = t >> 3;                     // 0..63 (512 threads)
    const int sc = (t & 7) ^ (srow & 7);         // swizzled chunk slot
    const int diag_n = qt;                       // this wave's diagonal tile
    const int i_tloc = (wave & 3) * 16 + l16;    // query pos within the tile
    const int nt = 32 - x;                       // 64-tiles 0 .. 31-x
    const int nt2 = (nt + 1) >> 1;               // 128-iterations (9..16)

    auto stage = [&](int n2) {                   // 4 loads -> vmcnt +4
        const int j0 = n2 * 128;                 // max j0+64+63 = 2047 (nt even)
        char* buf = smem + (n2 & 1) * 32768;     // or 1151+ (nt odd, in-bounds)
        gld_lds16(Kp + (size_t)(j0 + srow) * 64 + sc * 8,      buf + t * 16);
        gld_lds16(Kp + (size_t)(j0 + 64 + srow) * 64 + sc * 8, buf + 8192 + t * 16);
        gld_lds16(Vp + (size_t)srow * Tq + j0 + sc * 8,        buf + 16384 + t * 16);
        gld_lds16(Vp + (size_t)srow * Tq + j0 + 64 + sc * 8,   buf + 24576 + t * 16);
    };

    stage(0);
    for (int n2 = 0; n2 < nt2; n2++) {
        // gate: stage(n2) retired (issued a full iteration ago)
        asm volatile("s_waitcnt vmcnt(0)\n\ts_barrier" ::: "memory");
        if (n2 + 1 < nt2) stage(n2 + 1);         // post-barrier: WAR-safe ring-2
        char* cb = smem + (n2 & 1) * 32768;
#pragma unroll
        for (int s = 0; s < 2; s++) {
            const int tile = n2 * 2 + s;
            const u16* Ks = (const u16*)(cb + s * 8192);
            const f16* Vs = (const f16*)(cb + 16384 + s * 8192);
            if (tile < diag_n)
                flash_tile<false>(Ks, Vs, qf0, qf1, l16, quad, i_tloc, l_run, o_acc);
            else if (tile == diag_n)
                flash_tile<true>(Ks, Vs, qf0, qf1, l16, quad, i_tloc, l_run, o_acc);
            // tiles past the diagonal: skip compute, barrier already uniform
        }
    }

    // reduce l across the 4 quads sharing each query (once, not per tile)
    l_run += __shfl_xor(l_run, 16, 64);
    l_run += __shfl_xor(l_run, 32, 64);
    const float inv_l = 1.f / l_run;

    // epilogue: O^T -> O via padded LDS (stride 72), coalesced bf16 stores
    __syncthreads();                             // all waves done reading ring
    u16* Os = (u16*)smem;                        // 8 waves * 16 * 72 u16 = 18KB
#pragma unroll
    for (int td = 0; td < 4; td++) {
        u16x4 o;
#pragma unroll
        for (int r = 0; r < 4; r++) o[r] = f2bf(o_acc[td][r] * inv_l);
        *(u16x4*)&Os[wave * 1152 + l16 * 72 + td * 16 + quad * 4] = o;
    }
    __syncthreads();
    const int oi = lane >> 2, od = (lane & 3) * 16;
    u16x8 r0 = *(const u16x8*)&Os[wave * 1152 + oi * 72 + od];
    u16x8 r1 = *(const u16x8*)&Os[wave * 1152 + oi * 72 + od + 8];
    const size_t orow = ((size_t)b * Tq + q0w + (wave & 3) * 16 + oi) * Dq + h * 64 + od;
    *(u16x8*)&Ob[orow] = r0;
    *(u16x8*)&Ob[orow + 8] = r1;
}

// ---------------- launch ----------------
extern "C" void kernel_launch(void* const* d_in, const int* in_sizes, int n_in,
                              void* d_out, int out_size, void* d_ws, size_t ws_size,
                              hipStream_t stream) {
    const float* x     = (const float*)d_in[0];
    const float* cosT  = (const float*)d_in[1];
    const float* sinT  = (const float*)d_in[2];
    const float* Wqkv  = (const float*)d_in[3];
    const float* Wproj = (const float*)d_in[4];

    u16* xb     = (u16*)d_ws;                          // 8192*1024
    u16* wqkvb  = xb + (size_t)8192 * 1024;            // 3072*1024
    u16* wprojb = wqkvb + (size_t)3072 * 1024;         // 1024*1024
    u16* Qb     = wprojb + (size_t)1024 * 1024;        // 64*2048*64
    u16* Kb     = Qb + (size_t)64 * 2048 * 64;         // 64*2048*64
    f16* Vtg    = (f16*)(Kb + (size_t)64 * 2048 * 64); // 64*64*2048 (transposed)
    u16* attn   = (u16*)(Vtg + (size_t)64 * 64 * 2048);// 8192*1024

    cvt3_f32_bf16<<<12288, 256, 0, stream>>>(x, xb, 2097152,
                                             Wqkv, wqkvb, 786432,
                                             Wproj, wprojb, 262144);

    gemm_qkv<<<dim3(64, 24), 256, 0, stream>>>(xb, wqkvb, cosT, sinT, Qb, Kb, Vtg);
    flash<<<1024, 512, 0, stream>>>(Qb, Kb, Vtg, attn);
    gemm_bt<<<dim3(64, 8), 256, 0, stream>>>(attn, wprojb, (float*)d_out, 8192, 1024, 1024);
}